// Round 1
// baseline (1205.272 us; speedup 1.0000x reference)
//
#include <hip/hip_runtime.h>
#include <math.h>

// Problem constants (fixed by reference: enc (32,64,64,64) fp32, embed (512,64) fp32)
#define DQ 64
#define KQ 512
#define NVEC (32 * 64 * 64 * 64 / 64)      // 131072 vectors
#define QOUT_SIZE (NVEC * DQ)              // 8388608
#define LOSS_OFF QOUT_SIZE
#define IDX_OFF (QOUT_SIZE + 1)

// Init: zero the loss accumulator slot (d_out is poisoned 0xAA) and
// precompute e_sq[k] = sum_d embed[k][d]^2 into workspace.
__global__ void vq_init_kernel(const float* __restrict__ embed,
                               float* __restrict__ esq,
                               float* __restrict__ out) {
    int k = blockIdx.x * blockDim.x + threadIdx.x;
    if (k == 0) out[LOSS_OFF] = 0.0f;
    if (k < KQ) {
        const float4* e4 = (const float4*)(embed + k * DQ);
        float s0 = 0.f, s1 = 0.f, s2 = 0.f, s3 = 0.f;
#pragma unroll
        for (int j = 0; j < 16; j += 4) {
            float4 a = e4[j + 0], b = e4[j + 1], c = e4[j + 2], d = e4[j + 3];
            s0 = fmaf(a.x, a.x, s0); s0 = fmaf(a.y, a.y, s0); s0 = fmaf(a.z, a.z, s0); s0 = fmaf(a.w, a.w, s0);
            s1 = fmaf(b.x, b.x, s1); s1 = fmaf(b.y, b.y, s1); s1 = fmaf(b.z, b.z, s1); s1 = fmaf(b.w, b.w, s1);
            s2 = fmaf(c.x, c.x, s2); s2 = fmaf(c.y, c.y, s2); s2 = fmaf(c.z, c.z, s2); s2 = fmaf(c.w, c.w, s2);
            s3 = fmaf(d.x, d.x, s3); s3 = fmaf(d.y, d.y, s3); s3 = fmaf(d.z, d.z, s3); s3 = fmaf(d.w, d.w, s3);
        }
        esq[k] = (s0 + s1) + (s2 + s3);
    }
}

__global__ __launch_bounds__(256) void vq_main_kernel(const float* __restrict__ enc,
                                                      const float* __restrict__ embed,
                                                      const float* __restrict__ esq,
                                                      float* __restrict__ out) {
    const int v = blockIdx.x * blockDim.x + threadIdx.x;
    if (v >= NVEC) return;

    // Load this thread's vector (64 floats) into registers.
    const float4* xin = (const float4*)(enc + (size_t)v * DQ);
    float4 xr[16];
#pragma unroll
    for (int j = 0; j < 16; j++) xr[j] = xin[j];

    // x_sq = sum(x*x) (reference computes this per vector)
    float xs0 = 0.f, xs1 = 0.f, xs2 = 0.f, xs3 = 0.f;
#pragma unroll
    for (int j = 0; j < 16; j += 4) {
        float4 a = xr[j + 0], b = xr[j + 1], c = xr[j + 2], d = xr[j + 3];
        xs0 = fmaf(a.x, a.x, xs0); xs0 = fmaf(a.y, a.y, xs0); xs0 = fmaf(a.z, a.z, xs0); xs0 = fmaf(a.w, a.w, xs0);
        xs1 = fmaf(b.x, b.x, xs1); xs1 = fmaf(b.y, b.y, xs1); xs1 = fmaf(b.z, b.z, xs1); xs1 = fmaf(b.w, b.w, xs1);
        xs2 = fmaf(c.x, c.x, xs2); xs2 = fmaf(c.y, c.y, xs2); xs2 = fmaf(c.z, c.z, xs2); xs2 = fmaf(c.w, c.w, xs2);
        xs3 = fmaf(d.x, d.x, xs3); xs3 = fmaf(d.y, d.y, xs3); xs3 = fmaf(d.z, d.z, xs3); xs3 = fmaf(d.w, d.w, xs3);
    }
    const float x_sq = (xs0 + xs1) + (xs2 + xs3);

    const float4* e4 = (const float4*)embed;

    float best = 3.4e38f, best2 = 3.4e38f;
    int bidx = 0;

    for (int k = 0; k < KQ; k++) {
        float a0 = 0.f, a1 = 0.f, a2 = 0.f, a3 = 0.f;
#pragma unroll
        for (int j = 0; j < 16; j += 4) {
            // k and j are wave-uniform -> scalar (s_load) path, broadcast to lanes
            float4 e0 = e4[k * 16 + j + 0];
            float4 e1 = e4[k * 16 + j + 1];
            float4 e2 = e4[k * 16 + j + 2];
            float4 e3 = e4[k * 16 + j + 3];
            float4 x0 = xr[j + 0], x1 = xr[j + 1], x2 = xr[j + 2], x3 = xr[j + 3];
            a0 = fmaf(x0.x, e0.x, a0); a1 = fmaf(x1.x, e1.x, a1); a2 = fmaf(x2.x, e2.x, a2); a3 = fmaf(x3.x, e3.x, a3);
            a0 = fmaf(x0.y, e0.y, a0); a1 = fmaf(x1.y, e1.y, a1); a2 = fmaf(x2.y, e2.y, a2); a3 = fmaf(x3.y, e3.y, a3);
            a0 = fmaf(x0.z, e0.z, a0); a1 = fmaf(x1.z, e1.z, a1); a2 = fmaf(x2.z, e2.z, a2); a3 = fmaf(x3.z, e3.z, a3);
            a0 = fmaf(x0.w, e0.w, a0); a1 = fmaf(x1.w, e1.w, a1); a2 = fmaf(x2.w, e2.w, a2); a3 = fmaf(x3.w, e3.w, a3);
        }
        const float dot = (a0 + a1) + (a2 + a3);
        // Mirror reference: d2 = (x_sq - 2*dot) + e_sq[k]
        const float d2 = (x_sq - 2.0f * dot) + esq[k];
        if (d2 < best) {
            best2 = best; best = d2; bidx = k;
        } else if (d2 < best2) {
            best2 = d2;
        }
    }

    // Near-tie: re-rank in fp64 (effectively exact argmin). Rare (~0.02% of vectors).
    if (best2 - best < 1e-3f) {
        double bb = 1e300;
        int bi = 0;
        for (int k = 0; k < KQ; k++) {
            double acc = 0.0;
#pragma unroll 4
            for (int j = 0; j < 16; j++) {
                float4 e = e4[k * 16 + j];
                float4 x = xr[j];
                double d0 = (double)x.x - (double)e.x; acc = fma(d0, d0, acc);
                double d1 = (double)x.y - (double)e.y; acc = fma(d1, d1, acc);
                double d2d = (double)x.z - (double)e.z; acc = fma(d2d, d2d, acc);
                double d3 = (double)x.w - (double)e.w; acc = fma(d3, d3, acc);
            }
            if (acc < bb) { bb = acc; bi = k; }
        }
        bidx = bi;
    }

    // Epilogue: gather quantized row, write out, accumulate (q - x)^2.
    const float4* q4 = (const float4*)(embed + (size_t)bidx * DQ);
    float4* o4 = (float4*)(out + (size_t)v * DQ);
    float lsum = 0.f;
#pragma unroll
    for (int j = 0; j < 16; j++) {
        float4 q = q4[j];
        o4[j] = q;
        float4 x = xr[j];
        float d0 = q.x - x.x; lsum = fmaf(d0, d0, lsum);
        float d1 = q.y - x.y; lsum = fmaf(d1, d1, lsum);
        float d2 = q.z - x.z; lsum = fmaf(d2, d2, lsum);
        float d3 = q.w - x.w; lsum = fmaf(d3, d3, lsum);
    }
    out[IDX_OFF + v] = (float)bidx;

    // Loss reduction: wave shuffle -> block LDS -> one atomic per block.
#pragma unroll
    for (int off = 32; off > 0; off >>= 1) lsum += __shfl_down(lsum, off);

    __shared__ float red[4];
    const int lane = threadIdx.x & 63;
    const int wave = threadIdx.x >> 6;
    if (lane == 0) red[wave] = lsum;
    __syncthreads();
    if (threadIdx.x == 0) {
        float s = (red[0] + red[1]) + (red[2] + red[3]);
        // quantize_loss = codebook + commitment = 2 * mean((q - x)^2)
        atomicAdd(out + LOSS_OFF, s * (2.0f / (float)QOUT_SIZE));
    }
}

extern "C" void kernel_launch(void* const* d_in, const int* in_sizes, int n_in,
                              void* d_out, int out_size, void* d_ws, size_t ws_size,
                              hipStream_t stream) {
    const float* enc = (const float*)d_in[0];
    const float* embed = (const float*)d_in[1];
    float* out = (float*)d_out;
    float* esq = (float*)d_ws;   // 512 floats of scratch

    hipLaunchKernelGGL(vq_init_kernel, dim3(1), dim3(512), 0, stream, embed, esq, out);
    hipLaunchKernelGGL(vq_main_kernel, dim3(NVEC / 256), dim3(256), 0, stream,
                       enc, embed, esq, out);
}

// Round 2
// 906.079 us; speedup vs baseline: 1.3302x; 1.3302x over previous
//
#include <hip/hip_runtime.h>
#include <math.h>

// Problem constants (fixed by reference: enc (32,64,64,64) fp32, embed (512,64) fp32)
#define DQ 64
#define KQ 512
#define NVEC (32 * 64 * 64 * 64 / 64)      // 131072 vectors
#define QOUT_SIZE (NVEC * DQ)              // 8388608
#define LOSS_OFF QOUT_SIZE
#define IDX_OFF (QOUT_SIZE + 1)
#define TK 128                             // codebook rows per LDS tile (32 KB)

// Init: zero the loss accumulator slot (d_out is poisoned 0xAA) and
// precompute e_sq[k] = sum_d embed[k][d]^2 into workspace.
__global__ void vq_init_kernel(const float* __restrict__ embed,
                               float* __restrict__ esq,
                               float* __restrict__ out) {
    int k = blockIdx.x * blockDim.x + threadIdx.x;
    if (k == 0) out[LOSS_OFF] = 0.0f;
    if (k < KQ) {
        const float4* e4 = (const float4*)(embed + k * DQ);
        float s0 = 0.f, s1 = 0.f, s2 = 0.f, s3 = 0.f;
#pragma unroll
        for (int j = 0; j < 16; j += 4) {
            float4 a = e4[j + 0], b = e4[j + 1], c = e4[j + 2], d = e4[j + 3];
            s0 = fmaf(a.x, a.x, s0); s0 = fmaf(a.y, a.y, s0); s0 = fmaf(a.z, a.z, s0); s0 = fmaf(a.w, a.w, s0);
            s1 = fmaf(b.x, b.x, s1); s1 = fmaf(b.y, b.y, s1); s1 = fmaf(b.z, b.z, s1); s1 = fmaf(b.w, b.w, s1);
            s2 = fmaf(c.x, c.x, s2); s2 = fmaf(c.y, c.y, s2); s2 = fmaf(c.z, c.z, s2); s2 = fmaf(c.w, c.w, s2);
            s3 = fmaf(d.x, d.x, s3); s3 = fmaf(d.y, d.y, s3); s3 = fmaf(d.z, d.z, s3); s3 = fmaf(d.w, d.w, s3);
        }
        esq[k] = (s0 + s1) + (s2 + s3);
    }
}

__global__ __launch_bounds__(256) void vq_main_kernel(const float* __restrict__ enc,
                                                      const float* __restrict__ embed,
                                                      const float* __restrict__ esq,
                                                      float* __restrict__ out) {
    __shared__ float ecache[TK * DQ];      // 32 KB codebook tile
    __shared__ float esq_s[KQ];            // 2 KB e_sq (whole codebook)
    __shared__ float red[4];

    const int tid = threadIdx.x;
    const int v = blockIdx.x * blockDim.x + tid;   // grid is exactly NVEC threads

    // Stage e_sq once.
    esq_s[tid] = esq[tid];
    esq_s[tid + 256] = esq[tid + 256];

    // Load this thread's vector (64 floats) into registers.
    const float4* xin = (const float4*)(enc + (size_t)v * DQ);
    float4 xr[16];
#pragma unroll
    for (int j = 0; j < 16; j++) xr[j] = xin[j];

    // x_sq = sum(x*x) (reference computes this per vector)
    float xs0 = 0.f, xs1 = 0.f, xs2 = 0.f, xs3 = 0.f;
#pragma unroll
    for (int j = 0; j < 16; j += 4) {
        float4 a = xr[j + 0], b = xr[j + 1], c = xr[j + 2], d = xr[j + 3];
        xs0 = fmaf(a.x, a.x, xs0); xs0 = fmaf(a.y, a.y, xs0); xs0 = fmaf(a.z, a.z, xs0); xs0 = fmaf(a.w, a.w, xs0);
        xs1 = fmaf(b.x, b.x, xs1); xs1 = fmaf(b.y, b.y, xs1); xs1 = fmaf(b.z, b.z, xs1); xs1 = fmaf(b.w, b.w, xs1);
        xs2 = fmaf(c.x, c.x, xs2); xs2 = fmaf(c.y, c.y, xs2); xs2 = fmaf(c.z, c.z, xs2); xs2 = fmaf(c.w, c.w, xs2);
        xs3 = fmaf(d.x, d.x, xs3); xs3 = fmaf(d.y, d.y, xs3); xs3 = fmaf(d.z, d.z, xs3); xs3 = fmaf(d.w, d.w, xs3);
    }
    const float x_sq = (xs0 + xs1) + (xs2 + xs3);

    float best = 3.4e38f, best2 = 3.4e38f;
    int bidx = 0;

    const float4* eg4 = (const float4*)embed;     // global codebook as float4
    float4* ec4 = (float4*)ecache;                // LDS tile as float4

    for (int t = 0; t < KQ / TK; t++) {
        // Stage tile t: TK*DQ = 8192 floats = 2048 float4, 8 per thread, coalesced.
        __syncthreads();                           // protect previous tile's readers
#pragma unroll
        for (int i = 0; i < 8; i++) {
            ec4[tid + i * 256] = eg4[t * (TK * DQ / 4) + tid + i * 256];
        }
        __syncthreads();

#pragma unroll 4
        for (int kk = 0; kk < TK; kk++) {
            const float4* er = (const float4*)(ecache + kk * DQ);  // broadcast reads
            float a0 = 0.f, a1 = 0.f, a2 = 0.f, a3 = 0.f;
#pragma unroll
            for (int j = 0; j < 16; j += 4) {
                float4 e0 = er[j + 0], e1 = er[j + 1], e2 = er[j + 2], e3 = er[j + 3];
                float4 x0 = xr[j + 0], x1 = xr[j + 1], x2 = xr[j + 2], x3 = xr[j + 3];
                a0 = fmaf(x0.x, e0.x, a0); a1 = fmaf(x1.x, e1.x, a1); a2 = fmaf(x2.x, e2.x, a2); a3 = fmaf(x3.x, e3.x, a3);
                a0 = fmaf(x0.y, e0.y, a0); a1 = fmaf(x1.y, e1.y, a1); a2 = fmaf(x2.y, e2.y, a2); a3 = fmaf(x3.y, e3.y, a3);
                a0 = fmaf(x0.z, e0.z, a0); a1 = fmaf(x1.z, e1.z, a1); a2 = fmaf(x2.z, e2.z, a2); a3 = fmaf(x3.z, e3.z, a3);
                a0 = fmaf(x0.w, e0.w, a0); a1 = fmaf(x1.w, e1.w, a1); a2 = fmaf(x2.w, e2.w, a2); a3 = fmaf(x3.w, e3.w, a3);
            }
            const float dot = (a0 + a1) + (a2 + a3);
            const int kg = t * TK + kk;
            // Mirror reference: d2 = (x_sq - 2*dot) + e_sq[k]
            const float d2 = (x_sq - 2.0f * dot) + esq_s[kg];
            if (d2 < best) {
                best2 = best; best = d2; bidx = kg;
            } else if (d2 < best2) {
                best2 = d2;
            }
        }
    }

    // Near-tie: re-rank in fp64 (effectively exact argmin). Rare.
    if (best2 - best < 1e-3f) {
        double bb = 1e300;
        int bi = 0;
        for (int k = 0; k < KQ; k++) {
            double acc = 0.0;
#pragma unroll 4
            for (int j = 0; j < 16; j++) {
                float4 e = eg4[k * 16 + j];
                float4 x = xr[j];
                double d0 = (double)x.x - (double)e.x; acc = fma(d0, d0, acc);
                double d1 = (double)x.y - (double)e.y; acc = fma(d1, d1, acc);
                double d2d = (double)x.z - (double)e.z; acc = fma(d2d, d2d, acc);
                double d3 = (double)x.w - (double)e.w; acc = fma(d3, d3, acc);
            }
            if (acc < bb) { bb = acc; bi = k; }
        }
        bidx = bi;
    }

    // Epilogue: gather quantized row, write out, accumulate (q - x)^2.
    const float4* q4 = (const float4*)(embed + (size_t)bidx * DQ);
    float4* o4 = (float4*)(out + (size_t)v * DQ);
    float lsum = 0.f;
#pragma unroll
    for (int j = 0; j < 16; j++) {
        float4 q = q4[j];
        o4[j] = q;
        float4 x = xr[j];
        float d0 = q.x - x.x; lsum = fmaf(d0, d0, lsum);
        float d1 = q.y - x.y; lsum = fmaf(d1, d1, lsum);
        float d2 = q.z - x.z; lsum = fmaf(d2, d2, lsum);
        float d3 = q.w - x.w; lsum = fmaf(d3, d3, lsum);
    }
    out[IDX_OFF + v] = (float)bidx;

    // Loss reduction: wave shuffle -> block LDS -> one atomic per block.
#pragma unroll
    for (int off = 32; off > 0; off >>= 1) lsum += __shfl_down(lsum, off);

    const int lane = tid & 63;
    const int wave = tid >> 6;
    if (lane == 0) red[wave] = lsum;
    __syncthreads();
    if (tid == 0) {
        float s = (red[0] + red[1]) + (red[2] + red[3]);
        // quantize_loss = codebook + commitment = 2 * mean((q - x)^2)
        atomicAdd(out + LOSS_OFF, s * (2.0f / (float)QOUT_SIZE));
    }
}

extern "C" void kernel_launch(void* const* d_in, const int* in_sizes, int n_in,
                              void* d_out, int out_size, void* d_ws, size_t ws_size,
                              hipStream_t stream) {
    const float* enc = (const float*)d_in[0];
    const float* embed = (const float*)d_in[1];
    float* out = (float*)d_out;
    float* esq = (float*)d_ws;   // 512 floats of scratch

    hipLaunchKernelGGL(vq_init_kernel, dim3(1), dim3(512), 0, stream, embed, esq, out);
    hipLaunchKernelGGL(vq_main_kernel, dim3(NVEC / 256), dim3(256), 0, stream,
                       enc, embed, esq, out);
}

// Round 3
// 885.985 us; speedup vs baseline: 1.3604x; 1.0227x over previous
//
#include <hip/hip_runtime.h>
#include <math.h>

// Problem constants (fixed by reference: enc (32,64,64,64) fp32, embed (512,64) fp32)
#define DQ 64
#define KQ 512
#define NVEC (32 * 64 * 64 * 64 / 64)      // 131072 vectors
#define QOUT_SIZE (NVEC * DQ)              // 8388608
#define LOSS_OFF QOUT_SIZE
#define IDX_OFF (QOUT_SIZE + 1)
#define TK 128                             // codebook rows per LDS tile (32 KB)

// Init: zero the loss accumulator slot (d_out is poisoned 0xAA) and
// precompute e_sq[k] = sum_d embed[k][d]^2 into workspace.
__global__ void vq_init_kernel(const float* __restrict__ embed,
                               float* __restrict__ esq,
                               float* __restrict__ out) {
    int k = blockIdx.x * blockDim.x + threadIdx.x;
    if (k == 0) out[LOSS_OFF] = 0.0f;
    if (k < KQ) {
        const float4* e4 = (const float4*)(embed + k * DQ);
        float s0 = 0.f, s1 = 0.f, s2 = 0.f, s3 = 0.f;
#pragma unroll
        for (int j = 0; j < 16; j += 4) {
            float4 a = e4[j + 0], b = e4[j + 1], c = e4[j + 2], d = e4[j + 3];
            s0 = fmaf(a.x, a.x, s0); s0 = fmaf(a.y, a.y, s0); s0 = fmaf(a.z, a.z, s0); s0 = fmaf(a.w, a.w, s0);
            s1 = fmaf(b.x, b.x, s1); s1 = fmaf(b.y, b.y, s1); s1 = fmaf(b.z, b.z, s1); s1 = fmaf(b.w, b.w, s1);
            s2 = fmaf(c.x, c.x, s2); s2 = fmaf(c.y, c.y, s2); s2 = fmaf(c.z, c.z, s2); s2 = fmaf(c.w, c.w, s2);
            s3 = fmaf(d.x, d.x, s3); s3 = fmaf(d.y, d.y, s3); s3 = fmaf(d.z, d.z, s3); s3 = fmaf(d.w, d.w, s3);
        }
        esq[k] = (s0 + s1) + (s2 + s3);
    }
}

// __launch_bounds__(256, 2): min 2 waves/EU -> VGPR cap 256. Grid gives only
// 2 blocks/CU (2 waves/SIMD) anyway; without this the allocator targeted 8
// waves/SIMD (~64 VGPRs) and SPILLED xr[16] to scratch (R2: VGPR=68,
// WRITE_SIZE 2x ideal). x must stay register-resident.
__global__ __launch_bounds__(256, 2) void vq_main_kernel(const float* __restrict__ enc,
                                                         const float* __restrict__ embed,
                                                         const float* __restrict__ esq,
                                                         float* __restrict__ out) {
    __shared__ float ecache[TK * DQ];      // 32 KB codebook tile
    __shared__ float esq_s[KQ];            // 2 KB e_sq (whole codebook)
    __shared__ float red[4];

    const int tid = threadIdx.x;
    const int v = blockIdx.x * blockDim.x + tid;   // grid is exactly NVEC threads

    // Stage e_sq once.
    esq_s[tid] = esq[tid];
    esq_s[tid + 256] = esq[tid + 256];

    // Load this thread's vector (64 floats) into registers.
    const float4* xin = (const float4*)(enc + (size_t)v * DQ);
    float4 xr[16];
#pragma unroll
    for (int j = 0; j < 16; j++) xr[j] = xin[j];

    // x_sq = sum(x*x) (reference computes this per vector)
    float xs0 = 0.f, xs1 = 0.f, xs2 = 0.f, xs3 = 0.f;
#pragma unroll
    for (int j = 0; j < 16; j += 4) {
        float4 a = xr[j + 0], b = xr[j + 1], c = xr[j + 2], d = xr[j + 3];
        xs0 = fmaf(a.x, a.x, xs0); xs0 = fmaf(a.y, a.y, xs0); xs0 = fmaf(a.z, a.z, xs0); xs0 = fmaf(a.w, a.w, xs0);
        xs1 = fmaf(b.x, b.x, xs1); xs1 = fmaf(b.y, b.y, xs1); xs1 = fmaf(b.z, b.z, xs1); xs1 = fmaf(b.w, b.w, xs1);
        xs2 = fmaf(c.x, c.x, xs2); xs2 = fmaf(c.y, c.y, xs2); xs2 = fmaf(c.z, c.z, xs2); xs2 = fmaf(c.w, c.w, xs2);
        xs3 = fmaf(d.x, d.x, xs3); xs3 = fmaf(d.y, d.y, xs3); xs3 = fmaf(d.z, d.z, xs3); xs3 = fmaf(d.w, d.w, xs3);
    }
    const float x_sq = (xs0 + xs1) + (xs2 + xs3);

    float best = 3.4e38f, best2 = 3.4e38f;
    int bidx = 0;

    const float4* eg4 = (const float4*)embed;     // global codebook as float4
    float4* ec4 = (float4*)ecache;                // LDS tile as float4

    for (int t = 0; t < KQ / TK; t++) {
        // Stage tile t: TK*DQ = 8192 floats = 2048 float4, 8 per thread, coalesced.
        __syncthreads();                           // protect previous tile's readers
#pragma unroll
        for (int i = 0; i < 8; i++) {
            ec4[tid + i * 256] = eg4[t * (TK * DQ / 4) + tid + i * 256];
        }
        __syncthreads();

#pragma unroll 4
        for (int kk = 0; kk < TK; kk++) {
            const float4* er = (const float4*)(ecache + kk * DQ);  // broadcast reads
            float a0 = 0.f, a1 = 0.f, a2 = 0.f, a3 = 0.f;
#pragma unroll
            for (int j = 0; j < 16; j += 4) {
                float4 e0 = er[j + 0], e1 = er[j + 1], e2 = er[j + 2], e3 = er[j + 3];
                float4 x0 = xr[j + 0], x1 = xr[j + 1], x2 = xr[j + 2], x3 = xr[j + 3];
                a0 = fmaf(x0.x, e0.x, a0); a1 = fmaf(x1.x, e1.x, a1); a2 = fmaf(x2.x, e2.x, a2); a3 = fmaf(x3.x, e3.x, a3);
                a0 = fmaf(x0.y, e0.y, a0); a1 = fmaf(x1.y, e1.y, a1); a2 = fmaf(x2.y, e2.y, a2); a3 = fmaf(x3.y, e3.y, a3);
                a0 = fmaf(x0.z, e0.z, a0); a1 = fmaf(x1.z, e1.z, a1); a2 = fmaf(x2.z, e2.z, a2); a3 = fmaf(x3.z, e3.z, a3);
                a0 = fmaf(x0.w, e0.w, a0); a1 = fmaf(x1.w, e1.w, a1); a2 = fmaf(x2.w, e2.w, a2); a3 = fmaf(x3.w, e3.w, a3);
            }
            const float dot = (a0 + a1) + (a2 + a3);
            const int kg = t * TK + kk;
            // Mirror reference: d2 = (x_sq - 2*dot) + e_sq[k]
            const float d2 = (x_sq - 2.0f * dot) + esq_s[kg];
            if (d2 < best) {
                best2 = best; best = d2; bidx = kg;
            } else if (d2 < best2) {
                best2 = d2;
            }
        }
    }

    // Near-tie: re-rank in fp64 (effectively exact argmin). Rare (~0.02%).
    if (best2 - best < 1e-3f) {
        double bb = 1e300;
        int bi = 0;
        for (int k = 0; k < KQ; k++) {
            double acc = 0.0;
#pragma unroll 4
            for (int j = 0; j < 16; j++) {
                float4 e = eg4[k * 16 + j];
                float4 x = xr[j];
                double d0 = (double)x.x - (double)e.x; acc = fma(d0, d0, acc);
                double d1 = (double)x.y - (double)e.y; acc = fma(d1, d1, acc);
                double d2d = (double)x.z - (double)e.z; acc = fma(d2d, d2d, acc);
                double d3 = (double)x.w - (double)e.w; acc = fma(d3, d3, acc);
            }
            if (acc < bb) { bb = acc; bi = k; }
        }
        bidx = bi;
    }

    // Epilogue: gather quantized row, write out, accumulate (q - x)^2.
    const float4* q4 = (const float4*)(embed + (size_t)bidx * DQ);
    float4* o4 = (float4*)(out + (size_t)v * DQ);
    float lsum = 0.f;
#pragma unroll
    for (int j = 0; j < 16; j++) {
        float4 q = q4[j];
        o4[j] = q;
        float4 x = xr[j];
        float d0 = q.x - x.x; lsum = fmaf(d0, d0, lsum);
        float d1 = q.y - x.y; lsum = fmaf(d1, d1, lsum);
        float d2 = q.z - x.z; lsum = fmaf(d2, d2, lsum);
        float d3 = q.w - x.w; lsum = fmaf(d3, d3, lsum);
    }
    out[IDX_OFF + v] = (float)bidx;

    // Loss reduction: wave shuffle -> block LDS -> one atomic per block.
#pragma unroll
    for (int off = 32; off > 0; off >>= 1) lsum += __shfl_down(lsum, off);

    const int lane = tid & 63;
    const int wave = tid >> 6;
    if (lane == 0) red[wave] = lsum;
    __syncthreads();
    if (tid == 0) {
        float s = (red[0] + red[1]) + (red[2] + red[3]);
        // quantize_loss = codebook + commitment = 2 * mean((q - x)^2)
        atomicAdd(out + LOSS_OFF, s * (2.0f / (float)QOUT_SIZE));
    }
}

extern "C" void kernel_launch(void* const* d_in, const int* in_sizes, int n_in,
                              void* d_out, int out_size, void* d_ws, size_t ws_size,
                              hipStream_t stream) {
    const float* enc = (const float*)d_in[0];
    const float* embed = (const float*)d_in[1];
    float* out = (float*)d_out;
    float* esq = (float*)d_ws;   // 512 floats of scratch

    hipLaunchKernelGGL(vq_init_kernel, dim3(1), dim3(512), 0, stream, embed, esq, out);
    hipLaunchKernelGGL(vq_main_kernel, dim3(NVEC / 256), dim3(256), 0, stream,
                       enc, embed, esq, out);
}

// Round 4
// 707.910 us; speedup vs baseline: 1.7026x; 1.2516x over previous
//
#include <hip/hip_runtime.h>
#include <math.h>

// Problem constants (fixed by reference: enc (32,64,64,64) fp32, embed (512,64) fp32)
#define DQ 64
#define KQ 512
#define NVEC (32 * 64 * 64 * 64 / 64)      // 131072 vectors
#define QOUT_SIZE (NVEC * DQ)              // 8388608
#define LOSS_OFF QOUT_SIZE
#define IDX_OFF (QOUT_SIZE + 1)
#define TK 128                             // codebook rows per LDS tile (32 KB)

// Init: zero the loss accumulator slot (d_out is poisoned 0xAA) and
// precompute e_sq[k] = sum_d embed[k][d]^2 into workspace.
__global__ void vq_init_kernel(const float* __restrict__ embed,
                               float* __restrict__ esq,
                               float* __restrict__ out) {
    int k = blockIdx.x * blockDim.x + threadIdx.x;
    if (k == 0) out[LOSS_OFF] = 0.0f;
    if (k < KQ) {
        const float4* e4 = (const float4*)(embed + k * DQ);
        float s0 = 0.f, s1 = 0.f, s2 = 0.f, s3 = 0.f;
#pragma unroll
        for (int j = 0; j < 16; j += 4) {
            float4 a = e4[j + 0], b = e4[j + 1], c = e4[j + 2], d = e4[j + 3];
            s0 = fmaf(a.x, a.x, s0); s0 = fmaf(a.y, a.y, s0); s0 = fmaf(a.z, a.z, s0); s0 = fmaf(a.w, a.w, s0);
            s1 = fmaf(b.x, b.x, s1); s1 = fmaf(b.y, b.y, s1); s1 = fmaf(b.z, b.z, s1); s1 = fmaf(b.w, b.w, s1);
            s2 = fmaf(c.x, c.x, s2); s2 = fmaf(c.y, c.y, s2); s2 = fmaf(c.z, c.z, s2); s2 = fmaf(c.w, c.w, s2);
            s3 = fmaf(d.x, d.x, s3); s3 = fmaf(d.y, d.y, s3); s3 = fmaf(d.z, d.z, s3); s3 = fmaf(d.w, d.w, s3);
        }
        esq[k] = (s0 + s1) + (s2 + s3);
    }
}

// NOTE (R3 post-mortem): the fp64 re-rank loop below MUST be fully unrolled.
// With "#pragma unroll 4" xr[j] was indexed by a runtime j, which defeated
// SROA -> the whole xr array lived in SCRATCH for the entire kernel
// (VGPR=68, +32 MB spill writes, VALUBusy 20%). Constant indices only!
__global__ __launch_bounds__(256, 2) void vq_main_kernel(const float* __restrict__ enc,
                                                         const float* __restrict__ embed,
                                                         const float* __restrict__ esq,
                                                         float* __restrict__ out) {
    __shared__ float ecache[TK * DQ];      // 32 KB codebook tile
    __shared__ float esq_s[KQ];            // 2 KB e_sq (whole codebook)
    __shared__ float red[4];

    const int tid = threadIdx.x;
    const int v = blockIdx.x * blockDim.x + tid;   // grid is exactly NVEC threads

    // Stage e_sq once.
    esq_s[tid] = esq[tid];
    esq_s[tid + 256] = esq[tid + 256];

    // Load this thread's vector (64 floats) into registers.
    const float4* xin = (const float4*)(enc + (size_t)v * DQ);
    float4 xr[16];
#pragma unroll
    for (int j = 0; j < 16; j++) xr[j] = xin[j];

    // x_sq = sum(x*x) (reference computes this per vector)
    float xs0 = 0.f, xs1 = 0.f, xs2 = 0.f, xs3 = 0.f;
#pragma unroll
    for (int j = 0; j < 16; j += 4) {
        float4 a = xr[j + 0], b = xr[j + 1], c = xr[j + 2], d = xr[j + 3];
        xs0 = fmaf(a.x, a.x, xs0); xs0 = fmaf(a.y, a.y, xs0); xs0 = fmaf(a.z, a.z, xs0); xs0 = fmaf(a.w, a.w, xs0);
        xs1 = fmaf(b.x, b.x, xs1); xs1 = fmaf(b.y, b.y, xs1); xs1 = fmaf(b.z, b.z, xs1); xs1 = fmaf(b.w, b.w, xs1);
        xs2 = fmaf(c.x, c.x, xs2); xs2 = fmaf(c.y, c.y, xs2); xs2 = fmaf(c.z, c.z, xs2); xs2 = fmaf(c.w, c.w, xs2);
        xs3 = fmaf(d.x, d.x, xs3); xs3 = fmaf(d.y, d.y, xs3); xs3 = fmaf(d.z, d.z, xs3); xs3 = fmaf(d.w, d.w, xs3);
    }
    const float x_sq = (xs0 + xs1) + (xs2 + xs3);

    float best = 3.4e38f, best2 = 3.4e38f;
    int bidx = 0;

    const float4* eg4 = (const float4*)embed;     // global codebook as float4
    float4* ec4 = (float4*)ecache;                // LDS tile as float4

    for (int t = 0; t < KQ / TK; t++) {
        // Stage tile t: TK*DQ = 8192 floats = 2048 float4, 8 per thread, coalesced.
        __syncthreads();                           // protect previous tile's readers
#pragma unroll
        for (int i = 0; i < 8; i++) {
            ec4[tid + i * 256] = eg4[t * (TK * DQ / 4) + tid + i * 256];
        }
        __syncthreads();

#pragma unroll 4
        for (int kk = 0; kk < TK; kk++) {
            const float4* er = (const float4*)(ecache + kk * DQ);  // broadcast reads
            float a0 = 0.f, a1 = 0.f, a2 = 0.f, a3 = 0.f;
#pragma unroll
            for (int j = 0; j < 16; j += 4) {
                float4 e0 = er[j + 0], e1 = er[j + 1], e2 = er[j + 2], e3 = er[j + 3];
                float4 x0 = xr[j + 0], x1 = xr[j + 1], x2 = xr[j + 2], x3 = xr[j + 3];
                a0 = fmaf(x0.x, e0.x, a0); a1 = fmaf(x1.x, e1.x, a1); a2 = fmaf(x2.x, e2.x, a2); a3 = fmaf(x3.x, e3.x, a3);
                a0 = fmaf(x0.y, e0.y, a0); a1 = fmaf(x1.y, e1.y, a1); a2 = fmaf(x2.y, e2.y, a2); a3 = fmaf(x3.y, e3.y, a3);
                a0 = fmaf(x0.z, e0.z, a0); a1 = fmaf(x1.z, e1.z, a1); a2 = fmaf(x2.z, e2.z, a2); a3 = fmaf(x3.z, e3.z, a3);
                a0 = fmaf(x0.w, e0.w, a0); a1 = fmaf(x1.w, e1.w, a1); a2 = fmaf(x2.w, e2.w, a2); a3 = fmaf(x3.w, e3.w, a3);
            }
            const float dot = (a0 + a1) + (a2 + a3);
            const int kg = t * TK + kk;
            // Mirror reference: d2 = (x_sq - 2*dot) + e_sq[k]
            const float d2 = (x_sq - 2.0f * dot) + esq_s[kg];
            if (d2 < best) {
                best2 = best; best = d2; bidx = kg;
            } else if (d2 < best2) {
                best2 = d2;
            }
        }
    }

    // Near-tie: re-rank in fp64 (effectively exact argmin). Rare (~0.02%).
    // FULLY unrolled j so xr[] is only ever indexed by constants (see note).
    if (best2 - best < 1e-3f) {
        double bb = 1e300;
        int bi = 0;
        for (int k = 0; k < KQ; k++) {
            double acc = 0.0;
#pragma unroll
            for (int j = 0; j < 16; j++) {
                float4 e = eg4[k * 16 + j];
                float4 x = xr[j];
                double d0 = (double)x.x - (double)e.x; acc = fma(d0, d0, acc);
                double d1 = (double)x.y - (double)e.y; acc = fma(d1, d1, acc);
                double d2d = (double)x.z - (double)e.z; acc = fma(d2d, d2d, acc);
                double d3 = (double)x.w - (double)e.w; acc = fma(d3, d3, acc);
            }
            if (acc < bb) { bb = acc; bi = k; }
        }
        bidx = bi;
    }

    // Epilogue: gather quantized row, write out, accumulate (q - x)^2.
    const float4* q4 = (const float4*)(embed + (size_t)bidx * DQ);
    float4* o4 = (float4*)(out + (size_t)v * DQ);
    float lsum = 0.f;
#pragma unroll
    for (int j = 0; j < 16; j++) {
        float4 q = q4[j];
        o4[j] = q;
        float4 x = xr[j];
        float d0 = q.x - x.x; lsum = fmaf(d0, d0, lsum);
        float d1 = q.y - x.y; lsum = fmaf(d1, d1, lsum);
        float d2 = q.z - x.z; lsum = fmaf(d2, d2, lsum);
        float d3 = q.w - x.w; lsum = fmaf(d3, d3, lsum);
    }
    out[IDX_OFF + v] = (float)bidx;

    // Loss reduction: wave shuffle -> block LDS -> one atomic per block.
#pragma unroll
    for (int off = 32; off > 0; off >>= 1) lsum += __shfl_down(lsum, off);

    const int lane = tid & 63;
    const int wave = tid >> 6;
    if (lane == 0) red[wave] = lsum;
    __syncthreads();
    if (tid == 0) {
        float s = (red[0] + red[1]) + (red[2] + red[3]);
        // quantize_loss = codebook + commitment = 2 * mean((q - x)^2)
        atomicAdd(out + LOSS_OFF, s * (2.0f / (float)QOUT_SIZE));
    }
}

extern "C" void kernel_launch(void* const* d_in, const int* in_sizes, int n_in,
                              void* d_out, int out_size, void* d_ws, size_t ws_size,
                              hipStream_t stream) {
    const float* enc = (const float*)d_in[0];
    const float* embed = (const float*)d_in[1];
    float* out = (float*)d_out;
    float* esq = (float*)d_ws;   // 512 floats of scratch

    hipLaunchKernelGGL(vq_init_kernel, dim3(1), dim3(512), 0, stream, embed, esq, out);
    hipLaunchKernelGGL(vq_main_kernel, dim3(NVEC / 256), dim3(256), 0, stream,
                       enc, embed, esq, out);
}

// Round 5
// 236.318 us; speedup vs baseline: 5.1002x; 2.9956x over previous
//
#include <hip/hip_runtime.h>
#include <math.h>

// Problem constants (fixed by reference: enc (32,64,64,64) fp32, embed (512,64) fp32)
#define DQ 64
#define KQ 512
#define NVEC 131072
#define QOUT_SIZE (NVEC * DQ)              // 8388608
#define LOSS_OFF QOUT_SIZE
#define IDX_OFF (QOUT_SIZE + 1)

#define VPB 64                             // vectors per block (4 waves x 16)
#define NBLK (NVEC / VPB)                  // 2048 blocks
#define SC 128                             // codebook rows per LDS stage
#define LROW 72                            // LDS row stride in bf16 elems (+4 banks/row -> 2-way max)
#define TIE_THR 0.01f                      // fp64 re-rank when top-2 gap below this (err bound ~1e-3)

typedef __attribute__((ext_vector_type(8))) short short8;          // 8 bf16 = 1 MFMA A/B frag
typedef __attribute__((ext_vector_type(4))) float f32x4;           // MFMA C/D frag
typedef __attribute__((ext_vector_type(4))) unsigned short ushort4v;

static __device__ __forceinline__ unsigned short f2bf(float f) {   // RNE fp32->bf16
    unsigned u = __float_as_uint(f);
    u += 0x7fff + ((u >> 16) & 1);
    return (unsigned short)(u >> 16);
}
static __device__ __forceinline__ float bf2f(unsigned short h) {
    return __uint_as_float(((unsigned)h) << 16);
}

// Init: zero loss slot, precompute e_sq[k] into workspace.
__global__ void vq_init_kernel(const float* __restrict__ embed,
                               float* __restrict__ esq,
                               float* __restrict__ out) {
    int k = blockIdx.x * blockDim.x + threadIdx.x;
    if (k == 0) out[LOSS_OFF] = 0.0f;
    if (k < KQ) {
        const float4* e4 = (const float4*)(embed + k * DQ);
        float s = 0.f;
#pragma unroll
        for (int j = 0; j < 16; j++) {
            float4 a = e4[j];
            s = fmaf(a.x, a.x, s); s = fmaf(a.y, a.y, s);
            s = fmaf(a.z, a.z, s); s = fmaf(a.w, a.w, s);
        }
        esq[k] = s;
    }
}

// One wave handles 16 vectors x all 512 codes via mfma_f32_16x16x32_bf16.
// x and e are split hi/lo bf16; 8 MFMAs per 16-code tile accumulate the
// fp32 dot. Argmin: per-lane top-3 cascade + xor-shuffle merge; near-ties
// (gap < TIE_THR) resolved exactly in fp64 on <=3 candidates.
// R3 lesson: all register arrays indexed only by fully-unrolled constants.
__global__ __launch_bounds__(256, 2) void vq_mfma_kernel(const float* __restrict__ enc,
                                                         const float* __restrict__ embed,
                                                         const float* __restrict__ esq,
                                                         float* __restrict__ out) {
    __shared__ unsigned short eh_s[SC * LROW];   // 18 KB codebook hi tile
    __shared__ unsigned short el_s[SC * LROW];   // 18 KB codebook lo tile
    __shared__ float esq_s[KQ];                  // 2 KB
    __shared__ float xsq_s[4 * 16];
    __shared__ int bidx_s[4 * 16];

    const int tid = threadIdx.x;
    const int lane = tid & 63;
    const int w = tid >> 6;            // wave 0..3
    const int l15 = lane & 15;
    const int l4 = lane >> 4;          // 0..3
    const int vb = blockIdx.x * VPB + w * 16;

    // Stage e_sq once.
    esq_s[tid] = esq[tid];
    esq_s[tid + 256] = esq[tid + 256];

    // --- A fragments: row m = l15, dims chunk l4*8 (khalf0) and 32+l4*8 (khalf1)
    const int arow = vb + l15;
    const float4* xa = (const float4*)(enc + (size_t)arow * DQ + l4 * 8);
    const float4* xb = (const float4*)(enc + (size_t)arow * DQ + 32 + l4 * 8);
    float4 x0 = xa[0], x1 = xa[1];     // khalf0 dims l4*8+0..7
    float4 x2 = xb[0], x3 = xb[1];     // khalf1 dims 32+l4*8+0..7

    short8 ah0, al0, ah1, al1;
#define CVT(DH, DL, I, V) { unsigned short _h = f2bf(V); DH[I] = (short)_h; DL[I] = (short)f2bf((V) - bf2f(_h)); }
    CVT(ah0, al0, 0, x0.x) CVT(ah0, al0, 1, x0.y) CVT(ah0, al0, 2, x0.z) CVT(ah0, al0, 3, x0.w)
    CVT(ah0, al0, 4, x1.x) CVT(ah0, al0, 5, x1.y) CVT(ah0, al0, 6, x1.z) CVT(ah0, al0, 7, x1.w)
    CVT(ah1, al1, 0, x2.x) CVT(ah1, al1, 1, x2.y) CVT(ah1, al1, 2, x2.z) CVT(ah1, al1, 3, x2.w)
    CVT(ah1, al1, 4, x3.x) CVT(ah1, al1, 5, x3.y) CVT(ah1, al1, 6, x3.z) CVT(ah1, al1, 7, x3.w)

    // x_sq for row l15: partial over this lane's 16 dims, reduce across l4 groups.
    float ps = 0.f;
    ps = fmaf(x0.x, x0.x, ps); ps = fmaf(x0.y, x0.y, ps); ps = fmaf(x0.z, x0.z, ps); ps = fmaf(x0.w, x0.w, ps);
    ps = fmaf(x1.x, x1.x, ps); ps = fmaf(x1.y, x1.y, ps); ps = fmaf(x1.z, x1.z, ps); ps = fmaf(x1.w, x1.w, ps);
    ps = fmaf(x2.x, x2.x, ps); ps = fmaf(x2.y, x2.y, ps); ps = fmaf(x2.z, x2.z, ps); ps = fmaf(x2.w, x2.w, ps);
    ps = fmaf(x3.x, x3.x, ps); ps = fmaf(x3.y, x3.y, ps); ps = fmaf(x3.z, x3.z, ps); ps = fmaf(x3.w, x3.w, ps);
    ps += __shfl_xor(ps, 16);
    ps += __shfl_xor(ps, 32);
    if (l4 == 0) xsq_s[w * 16 + l15] = ps;
    __syncthreads();   // xsq_s + esq_s visible

    float xsqr[4];
#pragma unroll
    for (int r = 0; r < 4; r++) xsqr[r] = xsq_s[w * 16 + l4 * 4 + r];

    float b1[4], b2[4], b3[4];
    int i1[4], i2[4], i3[4];
#pragma unroll
    for (int r = 0; r < 4; r++) { b1[r] = b2[r] = b3[r] = 3.4e38f; i1[r] = i2[r] = i3[r] = 0; }

    const int crow = tid >> 1;             // 0..127: code row within stage
    const int cset = (tid & 1) * 32;       // dim half

    for (int t = 0; t < 4; t++) {
        __syncthreads();                    // protect previous stage's readers
        // Stage SC codes as bf16 hi/lo. 256 threads cover 128 rows x 2 dim-halves.
        const float4* src = (const float4*)(embed + (size_t)(t * SC + crow) * DQ + cset);
        unsigned short* hd = eh_s + crow * LROW + cset;
        unsigned short* ld = el_s + crow * LROW + cset;
#pragma unroll
        for (int q = 0; q < 8; q++) {
            float4 f = src[q];
            unsigned short h0 = f2bf(f.x), h1 = f2bf(f.y), h2 = f2bf(f.z), h3 = f2bf(f.w);
            ushort4v hv = { h0, h1, h2, h3 };
            ushort4v lv = { f2bf(f.x - bf2f(h0)), f2bf(f.y - bf2f(h1)),
                            f2bf(f.z - bf2f(h2)), f2bf(f.w - bf2f(h3)) };
            *(ushort4v*)(hd + q * 4) = hv;
            *(ushort4v*)(ld + q * 4) = lv;
        }
        __syncthreads();

#pragma unroll
        for (int s = 0; s < 8; s++) {
            const int cb = s * 16;
            const unsigned short* bh = eh_s + (cb + l15) * LROW + l4 * 8;
            const unsigned short* bl = el_s + (cb + l15) * LROW + l4 * 8;
            short8 bh0 = *(const short8*)(bh);
            short8 bh1 = *(const short8*)(bh + 32);
            short8 bl0 = *(const short8*)(bl);
            short8 bl1 = *(const short8*)(bl + 32);
            f32x4 acc = {0.f, 0.f, 0.f, 0.f};
            acc = __builtin_amdgcn_mfma_f32_16x16x32_bf16(ah0, bh0, acc, 0, 0, 0);
            acc = __builtin_amdgcn_mfma_f32_16x16x32_bf16(ah1, bh1, acc, 0, 0, 0);
            acc = __builtin_amdgcn_mfma_f32_16x16x32_bf16(al0, bh0, acc, 0, 0, 0);
            acc = __builtin_amdgcn_mfma_f32_16x16x32_bf16(al1, bh1, acc, 0, 0, 0);
            acc = __builtin_amdgcn_mfma_f32_16x16x32_bf16(ah0, bl0, acc, 0, 0, 0);
            acc = __builtin_amdgcn_mfma_f32_16x16x32_bf16(ah1, bl1, acc, 0, 0, 0);
            acc = __builtin_amdgcn_mfma_f32_16x16x32_bf16(al0, bl0, acc, 0, 0, 0);
            acc = __builtin_amdgcn_mfma_f32_16x16x32_bf16(al1, bl1, acc, 0, 0, 0);

            const int code = t * SC + cb + l15;       // C/D col = lane&15
            const float ev = esq_s[code];
#pragma unroll
            for (int r = 0; r < 4; r++) {             // C/D row = l4*4 + r
                float d2 = (xsqr[r] + ev) - 2.0f * acc[r];
                if (d2 < b1[r]) {
                    b3[r] = b2[r]; i3[r] = i2[r];
                    b2[r] = b1[r]; i2[r] = i1[r];
                    b1[r] = d2;    i1[r] = code;
                } else if (d2 < b2[r]) {
                    b3[r] = b2[r]; i3[r] = i2[r];
                    b2[r] = d2;    i2[r] = code;
                } else if (d2 < b3[r]) {
                    b3[r] = d2;    i3[r] = code;
                }
            }
        }
    }

    // Cross-lane merge of top-3 over the 16 cols (xor over lane&15 bits).
#pragma unroll
    for (int m = 1; m <= 8; m <<= 1) {
#pragma unroll
        for (int r = 0; r < 4; r++) {
            float c1 = __shfl_xor(b1[r], m), c2 = __shfl_xor(b2[r], m), c3 = __shfl_xor(b3[r], m);
            int j1 = __shfl_xor(i1[r], m), j2 = __shfl_xor(i2[r], m), j3 = __shfl_xor(i3[r], m);
#pragma unroll
            for (int ci = 0; ci < 3; ci++) {
                float cv = (ci == 0) ? c1 : (ci == 1) ? c2 : c3;
                int cj = (ci == 0) ? j1 : (ci == 1) ? j2 : j3;
                if (cv < b1[r]) {
                    b3[r] = b2[r]; i3[r] = i2[r];
                    b2[r] = b1[r]; i2[r] = i1[r];
                    b1[r] = cv;    i1[r] = cj;
                } else if (cv < b2[r]) {
                    b3[r] = b2[r]; i3[r] = i2[r];
                    b2[r] = cv;    i2[r] = cj;
                } else if (cv < b3[r]) {
                    b3[r] = cv;    i3[r] = cj;
                }
            }
        }
    }

    // Owner lanes (l15==0) finalize rows l4*4+r: fp64 re-rank near-ties, write idx.
    if (l15 == 0) {
#pragma unroll
        for (int r = 0; r < 4; r++) {
            const int row = l4 * 4 + r;
            const int v = vb + row;
            int bidx = i1[r];
            if (b2[r] - b1[r] < TIE_THR) {
                const float4* xe = (const float4*)(enc + (size_t)v * DQ);
                double bb = 1e300;
                int bsel = bidx;
                const int nc = (b3[r] - b1[r] < TIE_THR) ? 3 : 2;
                for (int ci = 0; ci < nc; ci++) {
                    const int c = (ci == 0) ? i1[r] : (ci == 1) ? i2[r] : i3[r];
                    const float4* ee = (const float4*)(embed + (size_t)c * DQ);
                    double acc = 0.0;
                    for (int j = 0; j < 16; j++) {      // global ptrs: runtime j is fine
                        float4 xx = xe[j], ez = ee[j];
                        double d0 = (double)xx.x - (double)ez.x; acc = fma(d0, d0, acc);
                        double d1 = (double)xx.y - (double)ez.y; acc = fma(d1, d1, acc);
                        double d2 = (double)xx.z - (double)ez.z; acc = fma(d2, d2, acc);
                        double d3 = (double)xx.w - (double)ez.w; acc = fma(d3, d3, acc);
                    }
                    if (acc < bb || (acc == bb && c < bsel)) { bb = acc; bsel = c; }
                }
                bidx = bsel;
            }
            out[IDX_OFF + v] = (float)bidx;
            bidx_s[w * 16 + row] = bidx;
        }
    }
    __syncthreads();

    // Epilogue: each lane writes its row's (l15) two 8-dim chunks of quantized
    // values and accumulates (q-x)^2 from the register-resident fp32 x.
    const int myv = vb + l15;
    const int qb = bidx_s[w * 16 + l15];
    const float4* qa = (const float4*)(embed + (size_t)qb * DQ + l4 * 8);
    const float4* qc = (const float4*)(embed + (size_t)qb * DQ + 32 + l4 * 8);
    float4 q0 = qa[0], q1 = qa[1], q2 = qc[0], q3 = qc[1];
    float4* oa = (float4*)(out + (size_t)myv * DQ + l4 * 8);
    float4* oc = (float4*)(out + (size_t)myv * DQ + 32 + l4 * 8);
    oa[0] = q0; oa[1] = q1;
    oc[0] = q2; oc[1] = q3;

    float ls = 0.f;
    float d;
    d = q0.x - x0.x; ls = fmaf(d, d, ls); d = q0.y - x0.y; ls = fmaf(d, d, ls);
    d = q0.z - x0.z; ls = fmaf(d, d, ls); d = q0.w - x0.w; ls = fmaf(d, d, ls);
    d = q1.x - x1.x; ls = fmaf(d, d, ls); d = q1.y - x1.y; ls = fmaf(d, d, ls);
    d = q1.z - x1.z; ls = fmaf(d, d, ls); d = q1.w - x1.w; ls = fmaf(d, d, ls);
    d = q2.x - x2.x; ls = fmaf(d, d, ls); d = q2.y - x2.y; ls = fmaf(d, d, ls);
    d = q2.z - x2.z; ls = fmaf(d, d, ls); d = q2.w - x2.w; ls = fmaf(d, d, ls);
    d = q3.x - x3.x; ls = fmaf(d, d, ls); d = q3.y - x3.y; ls = fmaf(d, d, ls);
    d = q3.z - x3.z; ls = fmaf(d, d, ls); d = q3.w - x3.w; ls = fmaf(d, d, ls);

#pragma unroll
    for (int off = 32; off > 0; off >>= 1) ls += __shfl_down(ls, off);
    if (lane == 0) atomicAdd(out + LOSS_OFF, ls * (2.0f / (float)QOUT_SIZE));
}

extern "C" void kernel_launch(void* const* d_in, const int* in_sizes, int n_in,
                              void* d_out, int out_size, void* d_ws, size_t ws_size,
                              hipStream_t stream) {
    const float* enc = (const float*)d_in[0];
    const float* embed = (const float*)d_in[1];
    float* out = (float*)d_out;
    float* esq = (float*)d_ws;   // 512 floats of scratch

    hipLaunchKernelGGL(vq_init_kernel, dim3(1), dim3(512), 0, stream, embed, esq, out);
    hipLaunchKernelGGL(vq_mfma_kernel, dim3(NBLK), dim3(256), 0, stream,
                       enc, embed, esq, out);
}